// Round 9
// baseline (41.907 us; speedup 1.0000x reference)
//
#include <hip/hip_runtime.h>
#include <hip/hip_bf16.h>

// RoI pooling (ROI-Align bilinear, A=7) on NHWC fp32 feature map.
// features_map: (1, 128, 128, 256) fp32
// boxes:        (2000, 4) int32  [x1, y1, x2, y2]
// out:          (2000, 1, 7, 7, 256) fp32
//
// Round-9: SAMPLE-ROW spatial sort (vs round-7's box sort, 34.4us).
// A sample row (box, py) = 7 samples sharing one fm row-pair (ys0, ys1).
// Counting-sort the 14000 rows by (ys0, x1/8); the main kernel walks rows
// in sorted order with chunked XCD swizzle. Concurrent rows per XCD then
// span ~2 distinct ys0 values -> instantaneous read working set ~384 KB
// (deep L2 residency + L1 dedup of the 24x average per-pixel reuse),
// vs box-sort's ~3.6MB. Output slot depends only on the sample's own box
// index => output bytes invariant to scatter order.
//
// Pipeline: memset bins -> row_hist -> row_prefix -> row_scatter -> main.

#define FM_H 128
#define FM_W 128
#define FM_C 256
#define ANCH 7
#define NSAMP (ANCH * ANCH)
#define NBINS 2048   // 128 ys0 values x 16 x-buckets (x1>>3)

typedef float f4 __attribute__((ext_vector_type(4)));

__device__ __forceinline__ int row_key(const int* boxes, int row) {
    const int box = row / ANCH;
    const int py  = row - box * ANCH;
    const int x1 = boxes[box * 4 + 0];
    const int y1 = boxes[box * 4 + 1];
    const int y2 = boxes[box * 4 + 3];
    const float spany = (float)(y2 - y1);
    float sy = ((float)py + 0.5f) * (spany / (float)ANCH) - 0.5f;
    sy = fminf(fmaxf(sy, 0.0f), fmaxf(spany - 1.0f, 0.0f));
    const int iy0 = (int)floorf(sy);
    const int ys0 = iy0 + y1;               // 0..127
    return (ys0 << 4) | (x1 >> 3);          // < 2048
}

__global__ __launch_bounds__(256) void row_hist(
    const int* __restrict__ boxes, int* __restrict__ bins, int n_rows)
{
    const int i = blockIdx.x * blockDim.x + threadIdx.x;
    if (i >= n_rows) return;
    atomicAdd(&bins[row_key(boxes, i)], 1);
}

__global__ __launch_bounds__(256) void row_prefix(
    const int* __restrict__ bins, int* __restrict__ cursors)
{
    __shared__ int partial[256];
    const int t = threadIdx.x;
    const int base = t * (NBINS / 256);     // 8 bins per thread
    int local[NBINS / 256];
    int s = 0;
    #pragma unroll
    for (int k = 0; k < NBINS / 256; ++k) { local[k] = s; s += bins[base + k]; }
    partial[t] = s;
    __syncthreads();
    if (t == 0) {
        int run = 0;
        for (int k = 0; k < 256; ++k) { int c = partial[k]; partial[k] = run; run += c; }
    }
    __syncthreads();
    const int off = partial[t];
    #pragma unroll
    for (int k = 0; k < NBINS / 256; ++k) cursors[base + k] = off + local[k];
}

__global__ __launch_bounds__(256) void row_scatter(
    const int* __restrict__ boxes, int* __restrict__ cursors,
    int* __restrict__ order, int n_rows)
{
    const int i = blockIdx.x * blockDim.x + threadIdx.x;
    if (i >= n_rows) return;
    const int pos = atomicAdd(&cursors[row_key(boxes, i)], 1);
    order[pos] = i;   // intra-bucket order nondeterministic; output invariant
}

__global__ __launch_bounds__(256) void roi_pool_kernel(
    const float* __restrict__ fm,
    const int* __restrict__ boxes,
    const int* __restrict__ order,
    float* __restrict__ out,
    int n_waves)   // N * 49 (one wave per sample; 7 consecutive waves = 1 row)
{
    // chunked bijective XCD swizzle: XCD k gets a contiguous wave range so
    // concurrent blocks on one XCD process neighboring sorted rows.
    const int nb  = gridDim.x;
    const int b   = blockIdx.x;
    const int q   = nb >> 3;
    const int r   = nb & 7;
    const int xcd = b & 7;
    const int idx = b >> 3;
    const int sb  = (xcd < r ? xcd * (q + 1) : r * (q + 1) + (xcd - r) * q) + idx;

    const int lane = threadIdx.x & 63;
    const int w = __builtin_amdgcn_readfirstlane((sb << 2) + (threadIdx.x >> 6));
    if (w >= n_waves) return;

    const int row_i = w / ANCH;          // sorted-row index
    const int px    = w - row_i * ANCH;
    const int R     = order[row_i];      // original row id = box*7 + py
    const int box   = R / ANCH;
    const int py    = R - box * ANCH;

    const int x1 = boxes[box * 4 + 0];
    const int y1 = boxes[box * 4 + 1];
    const int x2 = boxes[box * 4 + 2];
    const int y2 = boxes[box * 4 + 3];

    // ---- axis_samples(y1, y2) at index py ----
    const float spany = (float)(y2 - y1);
    float sy = ((float)py + 0.5f) * (spany / (float)ANCH) - 0.5f;
    sy = fminf(fmaxf(sy, 0.0f), fmaxf(spany - 1.0f, 0.0f));
    const int iy0 = (int)floorf(sy);
    const int iy1 = min(iy0 + 1, y2 - y1 - 1);
    const float fy = sy - (float)iy0;
    const int ys0 = iy0 + y1;
    const int ys1 = iy1 + y1;

    // ---- axis_samples(x1, x2) at index px ----
    const float spanx = (float)(x2 - x1);
    float sx = ((float)px + 0.5f) * (spanx / (float)ANCH) - 0.5f;
    sx = fminf(fmaxf(sx, 0.0f), fmaxf(spanx - 1.0f, 0.0f));
    const int ix0 = (int)floorf(sx);
    const int ix1 = min(ix0 + 1, x2 - x1 - 1);
    const float fx = sx - (float)ix0;
    const int xs0 = ix0 + x1;
    const int xs1 = ix1 + x1;

    const f4* p00 = (const f4*)(fm + ((size_t)ys0 * FM_W + xs0) * FM_C);
    const f4* p01 = (const f4*)(fm + ((size_t)ys0 * FM_W + xs1) * FM_C);
    const f4* p10 = (const f4*)(fm + ((size_t)ys1 * FM_W + xs0) * FM_C);
    const f4* p11 = (const f4*)(fm + ((size_t)ys1 * FM_W + xs1) * FM_C);

    const f4 v00 = p00[lane];
    const f4 v01 = p01[lane];
    const f4 v10 = p10[lane];
    const f4 v11 = p11[lane];

    const float gx = 1.0f - fx;
    const float gy = 1.0f - fy;

    // Match reference order: x-lerp then y-lerp
    f4 res;
    #pragma unroll
    for (int c = 0; c < 4; ++c) {
        float top = v00[c] * gx + v01[c] * fx;
        float bot = v10[c] * gx + v11[c] * fx;
        res[c] = top * gy + bot * fy;
    }

    // write at ORIGINAL sample position => output independent of sort order
    f4* dst = (f4*)(out + ((size_t)box * NSAMP + py * ANCH + px) * FM_C);
    __builtin_nontemporal_store(res, &dst[lane]);
}

extern "C" void kernel_launch(void* const* d_in, const int* in_sizes, int n_in,
                              void* d_out, int out_size, void* d_ws, size_t ws_size,
                              hipStream_t stream) {
    const float* fm    = (const float*)d_in[0];   // (1,128,128,256) fp32
    const int*   boxes = (const int*)d_in[1];     // (N,4) int32
    // d_in[2] = anchor_size scalar (7); layout constants hard-coded to setup.

    const int N = in_sizes[1] / 4;
    const int n_rows  = N * ANCH;                 // 14000
    const int n_waves = N * NSAMP;                // 98000

    float* out = (float*)d_out;

    int* ws      = (int*)d_ws;
    int* bins    = ws;                 // [NBINS]
    int* cursors = ws + NBINS;         // [NBINS]
    int* order   = ws + 2 * NBINS;     // [n_rows]

    hipMemsetAsync(bins, 0, NBINS * sizeof(int), stream);

    const int sort_blocks = (n_rows + 255) / 256;
    row_hist   <<<sort_blocks, 256, 0, stream>>>(boxes, bins, n_rows);
    row_prefix <<<1,           256, 0, stream>>>(bins, cursors);
    row_scatter<<<sort_blocks, 256, 0, stream>>>(boxes, cursors, order, n_rows);

    const int threads = 256;                      // 4 waves/block
    const int grid = (n_waves + 3) / 4;           // one wave per sample
    roi_pool_kernel<<<grid, threads, 0, stream>>>(fm, boxes, order, out, n_waves);
}